// Round 1
// baseline (74.886 us; speedup 1.0000x reference)
//
#include <hip/hip_runtime.h>
#include <hip/hip_bf16.h>

#define D_MODEL 256
#define D_K 128
#define BM 64
#define BK 32
#define MAXM 112

__device__ inline int lbound(const int* __restrict__ p, int stride, int n, int val) {
    int lo = 0, hi = n;
    while (lo < hi) {
        int mid = (lo + hi) >> 1;
        if (p[(size_t)mid * stride] < val) lo = mid + 1; else hi = mid;
    }
    return lo;
}

// ---------------- QKV projection: fp32 tiled GEMM ----------------
// grid (n/BM, 3), block 256. Computes Qs = (A@Wq+bq)/sqrt(128), K = A@Wk+bk, V = A@Wv+bv
__global__ __launch_bounds__(256) void qkv_gemm(
    const float* __restrict__ A,
    const float* __restrict__ Wq, const float* __restrict__ bq,
    const float* __restrict__ Wk, const float* __restrict__ bk,
    const float* __restrict__ Wv, const float* __restrict__ bv,
    float* __restrict__ Qs, float* __restrict__ Ko, float* __restrict__ Vo, int n)
{
    __shared__ float As[BM][BK + 1];   // [m][k], +1 pad: conflict-free stores
    __shared__ float Ws[BK][D_K];      // [k][col], float4-aligned

    const int tid = threadIdx.x;
    const int which = blockIdx.y;
    const float* W; const float* bias; float* out;
    float oscale = 1.0f;
    if (which == 0)      { W = Wq; bias = bq; out = Qs; oscale = 0.08838834764831845f; } // 1/sqrt(128)
    else if (which == 1) { W = Wk; bias = bk; out = Ko; }
    else                 { W = Wv; bias = bv; out = Vo; }

    const int rowBase = blockIdx.x * BM;
    const int tx = tid & 15;   // col group: 8 cols
    const int ty = tid >> 4;   // row group: 4 rows

    float acc[4][8];
    #pragma unroll
    for (int i = 0; i < 4; ++i)
        #pragma unroll
        for (int j = 0; j < 8; ++j) acc[i][j] = 0.f;

    for (int k0 = 0; k0 < D_MODEL; k0 += BK) {
        // A tile: 64x32 floats, 8 per thread, coalesced in 128B rows
        #pragma unroll
        for (int l = 0; l < 8; ++l) {
            int e = tid + l * 256;
            int r = e >> 5, c = e & 31;
            As[r][c] = A[(size_t)(rowBase + r) * D_MODEL + k0 + c];
        }
        // W tile: 32x128 floats, 4 float4 per thread, coalesced
        #pragma unroll
        for (int l = 0; l < 4; ++l) {
            int e4 = tid + l * 256;
            int off = e4 << 2;
            int kk = off >> 7, col = off & 127;
            *(float4*)&Ws[kk][col] = *(const float4*)&W[(size_t)(k0 + kk) * D_K + col];
        }
        __syncthreads();
        #pragma unroll
        for (int kk = 0; kk < BK; ++kk) {
            float av[4];
            #pragma unroll
            for (int i = 0; i < 4; ++i) av[i] = As[ty * 4 + i][kk];
            float4 w0 = *(const float4*)&Ws[kk][tx * 8];
            float4 w1 = *(const float4*)&Ws[kk][tx * 8 + 4];
            float wv[8] = {w0.x, w0.y, w0.z, w0.w, w1.x, w1.y, w1.z, w1.w};
            #pragma unroll
            for (int i = 0; i < 4; ++i)
                #pragma unroll
                for (int j = 0; j < 8; ++j)
                    acc[i][j] += av[i] * wv[j];
        }
        __syncthreads();
    }

    float bb[8];
    #pragma unroll
    for (int j = 0; j < 8; ++j) bb[j] = bias[tx * 8 + j];

    #pragma unroll
    for (int i = 0; i < 4; ++i) {
        int row = rowBase + ty * 4 + i;
        float* orow = out + (size_t)row * D_K + tx * 8;
        float4 o0, o1;
        o0.x = (acc[i][0] + bb[0]) * oscale;
        o0.y = (acc[i][1] + bb[1]) * oscale;
        o0.z = (acc[i][2] + bb[2]) * oscale;
        o0.w = (acc[i][3] + bb[3]) * oscale;
        o1.x = (acc[i][4] + bb[4]) * oscale;
        o1.y = (acc[i][5] + bb[5]) * oscale;
        o1.z = (acc[i][6] + bb[6]) * oscale;
        o1.w = (acc[i][7] + bb[7]) * oscale;
        *(float4*)&orow[0] = o0;
        *(float4*)&orow[4] = o1;
    }
}

// ---------------- Per-molecule attention + pooling (fast path, m <= MAXM) ----------------
// One block per molecule. mol_emb = sum_j (colsum_j of softmax) * V_j
__global__ __launch_bounds__(256) void attn_fast(
    const int* __restrict__ midx,
    const float* __restrict__ Qs, const float* __restrict__ Kf, const float* __restrict__ Vf,
    float* __restrict__ out, int n)
{
    __shared__ float S[MAXM][MAXM + 1];
    __shared__ float rinv[MAXM];
    __shared__ float csum[MAXM];

    const int tid = threadIdx.x;
    const int mol = blockIdx.x;
    // int64 vs int32 detection: sorted int64's high words are 0, so last int32 slot == 0
    const int stride = (midx[n - 1] == 0) ? 2 : 1;

    const int start = lbound(midx, stride, n, mol);
    const int end   = lbound(midx, stride, n, mol + 1);
    const int m = end - start;

    if (m == 0) {
        if (tid < D_K) out[(size_t)mol * D_K + tid] = 0.f;
        return;
    }
    if (m > MAXM) return;  // slow kernel handles

    // scores: S[i][j] = Qs[start+i] . K[start+j]  (scale folded into Qs)
    const int mm = m * m;
    for (int p = tid; p < mm; p += 256) {
        int i = p / m, j = p - i * m;
        const float4* q = (const float4*)(Qs + (size_t)(start + i) * D_K);
        const float4* k = (const float4*)(Kf + (size_t)(start + j) * D_K);
        float acc = 0.f;
        #pragma unroll
        for (int t = 0; t < D_K / 4; ++t) {
            float4 a = q[t], b = k[t];
            acc += a.x * b.x + a.y * b.y + a.z * b.z + a.w * b.w;
        }
        S[i][j] = acc;
    }
    __syncthreads();

    // row softmax (store exp, keep 1/rowsum)
    if (tid < m) {
        const int i = tid;
        float mx = -3.4e38f;
        for (int j = 0; j < m; ++j) mx = fmaxf(mx, S[i][j]);
        float sum = 0.f;
        for (int j = 0; j < m; ++j) { float e = __expf(S[i][j] - mx); S[i][j] = e; sum += e; }
        rinv[i] = 1.f / sum;
    }
    __syncthreads();

    // column sums of normalized weights
    if (tid < m) {
        const int j = tid;
        float acc = 0.f;
        for (int i = 0; i < m; ++i) acc += S[i][j] * rinv[i];
        csum[j] = acc;
    }
    __syncthreads();

    // emb[d] = sum_j csum[j] * V[start+j][d]
    if (tid < D_K) {
        const int d = tid;
        float acc = 0.f;
        for (int j = 0; j < m; ++j) acc += csum[j] * Vf[(size_t)(start + j) * D_K + d];
        out[(size_t)mol * D_K + d] = acc;
    }
}

// ---------------- Slow fallback for m > MAXM (correct for any m; expected never to trigger) ----------------
__global__ __launch_bounds__(256) void attn_slow(
    const int* __restrict__ midx,
    const float* __restrict__ Qs, const float* __restrict__ Kf, const float* __restrict__ Vf,
    float* __restrict__ out, float* __restrict__ ML, int n)
{
    __shared__ float emb[D_K];
    const int tid = threadIdx.x;
    const int mol = blockIdx.x;
    const int stride = (midx[n - 1] == 0) ? 2 : 1;
    const int start = lbound(midx, stride, n, mol);
    const int end   = lbound(midx, stride, n, mol + 1);
    const int m = end - start;
    if (m <= MAXM) return;  // fast kernel handled (incl. m==0)

    if (tid < D_K) emb[tid] = 0.f;
    float* Mv = ML;
    float* Lv = ML + n;

    // phase 1: per-row online max + expsum
    for (int i = tid; i < m; i += 256) {
        const float4* q = (const float4*)(Qs + (size_t)(start + i) * D_K);
        float mx = -3.4e38f, sum = 0.f;
        for (int j = 0; j < m; ++j) {
            const float4* k = (const float4*)(Kf + (size_t)(start + j) * D_K);
            float s = 0.f;
            #pragma unroll
            for (int t = 0; t < D_K / 4; ++t) {
                float4 a = q[t], b = k[t];
                s += a.x * b.x + a.y * b.y + a.z * b.z + a.w * b.w;
            }
            if (s > mx) { sum = sum * __expf(mx - s) + 1.f; mx = s; }
            else        { sum += __expf(s - mx); }
        }
        Mv[start + i] = mx;
        Lv[start + i] = 1.f / sum;
    }
    __threadfence_block();
    __syncthreads();

    // phase 2: column sums, accumulate emb
    for (int j = tid; j < m; j += 256) {
        const float4* k = (const float4*)(Kf + (size_t)(start + j) * D_K);
        float cj = 0.f;
        for (int i = 0; i < m; ++i) {
            const float4* q = (const float4*)(Qs + (size_t)(start + i) * D_K);
            float s = 0.f;
            #pragma unroll
            for (int t = 0; t < D_K / 4; ++t) {
                float4 a = q[t], b = k[t];
                s += a.x * b.x + a.y * b.y + a.z * b.z + a.w * b.w;
            }
            cj += __expf(s - Mv[start + i]) * Lv[start + i];
        }
        const float* v = Vf + (size_t)(start + j) * D_K;
        for (int d = 0; d < D_K; ++d) atomicAdd(&emb[d], cj * v[d]);
    }
    __syncthreads();
    if (tid < D_K) out[(size_t)mol * D_K + tid] = emb[tid];
}

extern "C" void kernel_launch(void* const* d_in, const int* in_sizes, int n_in,
                              void* d_out, int out_size, void* d_ws, size_t ws_size,
                              hipStream_t stream) {
    const float* frag = (const float*)d_in[0];
    const int*   midx = (const int*)d_in[1];
    const float* Wq = (const float*)d_in[2];
    const float* bq = (const float*)d_in[3];
    const float* Wk = (const float*)d_in[4];
    const float* bk = (const float*)d_in[5];
    const float* Wv = (const float*)d_in[6];
    const float* bv = (const float*)d_in[7];
    float* out = (float*)d_out;

    const int n = in_sizes[1];          // 8192 rows
    const int nmol = out_size / D_K;    // 512 molecules

    float* Qs = (float*)d_ws;
    float* Ko = Qs + (size_t)n * D_K;
    float* Vo = Ko + (size_t)n * D_K;
    float* ML = Vo + (size_t)n * D_K;   // 2*n floats for slow path

    qkv_gemm<<<dim3(n / BM, 3), 256, 0, stream>>>(frag, Wq, bq, Wk, bk, Wv, bv, Qs, Ko, Vo, n);
    attn_fast<<<nmol, 256, 0, stream>>>(midx, Qs, Ko, Vo, out, n);
    attn_slow<<<nmol, 256, 0, stream>>>(midx, Qs, Ko, Vo, out, ML, n);
}

// Round 3
// 59.691 us; speedup vs baseline: 1.2546x; 1.2546x over previous
//
#include <hip/hip_runtime.h>
#include <hip/hip_bf16.h>

#define D_MODEL 256
#define D_K 128
#define MAXM 64

typedef short bf16x8 __attribute__((ext_vector_type(8)));
typedef float f32x4 __attribute__((ext_vector_type(4)));

__device__ inline unsigned short f2bf(float x) {
    union { float f; unsigned u; } v; v.f = x;
    unsigned r = v.u + 0x7FFFu + ((v.u >> 16) & 1u);  // RNE (inputs are finite)
    return (unsigned short)(r >> 16);
}

__device__ inline int lbound(const int* __restrict__ p, int stride, int n, int val) {
    int lo = 0, hi = n;
    while (lo < hi) {
        int mid = (lo + hi) >> 1;
        if (p[(size_t)mid * stride] < val) lo = mid + 1; else hi = mid;
    }
    return lo;
}

// ---------------- pack: A fp32 -> bf16 row-major; W fp32 [k][c] -> bf16 Wt [c][k]; biases (q-scaled) ----------------
__global__ __launch_bounds__(256) void pack_kernel(
    const float* __restrict__ A,
    const float* __restrict__ Wq, const float* __restrict__ bq,
    const float* __restrict__ Wk, const float* __restrict__ bk,
    const float* __restrict__ Wv, const float* __restrict__ bv,
    unsigned short* __restrict__ Abf, unsigned short* __restrict__ Wt,
    float* __restrict__ Bias, int n)
{
    const int tid = threadIdx.x;
    const int blk = blockIdx.x;
    const int nAblocks = (n * D_MODEL) / 2048;
    const float qscale = 0.08838834764831845f; // 1/sqrt(128)

    if (blk < nAblocks) {
        size_t base = (size_t)blk * 2048 + (size_t)tid * 8;
        float4 a0 = *(const float4*)&A[base];
        float4 a1 = *(const float4*)&A[base + 4];
        unsigned short o[8] = {f2bf(a0.x), f2bf(a0.y), f2bf(a0.z), f2bf(a0.w),
                               f2bf(a1.x), f2bf(a1.y), f2bf(a1.z), f2bf(a1.w)};
        *(uint4*)&Abf[base] = *(const uint4*)o;
    } else if (blk < nAblocks + 96) {
        // 3*256*128 = 98304 elems, 96 blocks * 256 thr * 4 elems
        int e = (blk - nAblocks) * 1024 + tid * 4;
        int which = e >> 15;
        int rem = e & 32767;
        int r = rem >> 7, c = rem & 127;   // r = k index, c..c+3 = col indices
        const float* W = which == 0 ? Wq : (which == 1 ? Wk : Wv);
        float sc = (which == 0) ? qscale : 1.0f;
        float4 w = *(const float4*)&W[(size_t)r * D_K + c];
        unsigned short* dst = Wt + (size_t)which * D_K * D_MODEL;
        dst[(size_t)(c + 0) * D_MODEL + r] = f2bf(w.x * sc);
        dst[(size_t)(c + 1) * D_MODEL + r] = f2bf(w.y * sc);
        dst[(size_t)(c + 2) * D_MODEL + r] = f2bf(w.z * sc);
        dst[(size_t)(c + 3) * D_MODEL + r] = f2bf(w.w * sc);
    } else {
        // bias: 384 elements, 256 threads -> stride loop (round-2 bug: V bias was never filled)
        for (int t = tid; t < 3 * D_K; t += 256) {
            int which = t >> 7, c = t & 127;
            const float* b = which == 0 ? bq : (which == 1 ? bk : bv);
            Bias[t] = b[c] * ((which == 0) ? qscale : 1.0f);
        }
    }
}

// ---------------- QKV projection: bf16 MFMA, fragments loaded straight from global ----------------
// grid (n/32, 3), block 256 = 4 waves; wave tile 16 rows x 64 cols
__global__ __launch_bounds__(256) void qkv_mfma(
    const unsigned short* __restrict__ Abf, const unsigned short* __restrict__ Wt,
    const float* __restrict__ Bias,
    float* __restrict__ Qs, float* __restrict__ Ko, float* __restrict__ Vo, int n)
{
    const int which = blockIdx.y;
    float* out = which == 0 ? Qs : (which == 1 ? Ko : Vo);
    const unsigned short* Wtw = Wt + (size_t)which * D_K * D_MODEL;

    const int tid  = threadIdx.x;
    const int wave = tid >> 6;
    const int lane = tid & 63;
    const int rowBase = blockIdx.x * 32 + (wave >> 1) * 16;
    const int colBase = (wave & 1) * 64;
    const int lr = lane & 15;          // A-row / B-col within tile
    const int lk = (lane >> 4) * 8;    // k sub-offset

    f32x4 acc0 = {0.f, 0.f, 0.f, 0.f};
    f32x4 acc1 = {0.f, 0.f, 0.f, 0.f};
    f32x4 acc2 = {0.f, 0.f, 0.f, 0.f};
    f32x4 acc3 = {0.f, 0.f, 0.f, 0.f};

    const unsigned short* aRow = Abf + (size_t)(rowBase + lr) * D_MODEL + lk;
    const unsigned short* bCol = Wtw + (size_t)(colBase + lr) * D_MODEL + lk;

    #pragma unroll
    for (int k0 = 0; k0 < D_MODEL; k0 += 32) {
        bf16x8 af = *(const bf16x8*)(aRow + k0);
        bf16x8 b0 = *(const bf16x8*)(bCol + 0 * 16 * D_MODEL + k0);
        bf16x8 b1 = *(const bf16x8*)(bCol + 1 * 16 * D_MODEL + k0);
        bf16x8 b2 = *(const bf16x8*)(bCol + 2 * 16 * D_MODEL + k0);
        bf16x8 b3 = *(const bf16x8*)(bCol + 3 * 16 * D_MODEL + k0);
        acc0 = __builtin_amdgcn_mfma_f32_16x16x32_bf16(af, b0, acc0, 0, 0, 0);
        acc1 = __builtin_amdgcn_mfma_f32_16x16x32_bf16(af, b1, acc1, 0, 0, 0);
        acc2 = __builtin_amdgcn_mfma_f32_16x16x32_bf16(af, b2, acc2, 0, 0, 0);
        acc3 = __builtin_amdgcn_mfma_f32_16x16x32_bf16(af, b3, acc3, 0, 0, 0);
    }

    const int orow = rowBase + (lane >> 4) * 4;   // C/D: row=(lane>>4)*4+r, col=lane&15 (m89-verified)
    f32x4 accs[4] = {acc0, acc1, acc2, acc3};
    #pragma unroll
    for (int t = 0; t < 4; ++t) {
        int col = colBase + t * 16 + lr;
        float bb = Bias[which * D_K + col];
        #pragma unroll
        for (int r = 0; r < 4; ++r)
            out[(size_t)(orow + r) * D_K + col] = accs[t][r] + bb;
    }
}

// ---------------- Per-molecule attention + pooling (merged fast/slow) ----------------
__global__ __launch_bounds__(256) void attn_pool(
    const int* __restrict__ midx,
    const float* __restrict__ Qs, const float* __restrict__ Kf, const float* __restrict__ Vf,
    float* __restrict__ out, float* __restrict__ ML, int n)
{
    __shared__ float S[MAXM][MAXM + 1];
    __shared__ float rinv[MAXM];
    __shared__ float csum[MAXM];

    const int tid = threadIdx.x;
    const int mol = blockIdx.x;
    // int64 detection: sorted int64 high words are 0 -> last int32 slot == 0
    const int stride = (midx[n - 1] == 0) ? 2 : 1;
    const int start = lbound(midx, stride, n, mol);
    const int end   = lbound(midx, stride, n, mol + 1);
    const int m = end - start;

    if (m == 0) {
        if (tid < D_K) out[(size_t)mol * D_K + tid] = 0.f;
        return;
    }

    if (m <= MAXM) {
        // scores S[i][j] = Qs[start+i] . K[start+j]   (1/sqrt(dk) folded into Qs)
        const int mm = m * m;
        for (int p = tid; p < mm; p += 256) {
            int i = p / m, j = p - i * m;
            const float4* q = (const float4*)(Qs + (size_t)(start + i) * D_K);
            const float4* k = (const float4*)(Kf + (size_t)(start + j) * D_K);
            float acc = 0.f;
            #pragma unroll
            for (int t = 0; t < D_K / 4; ++t) {
                float4 a = q[t], b = k[t];
                acc += a.x * b.x + a.y * b.y + a.z * b.z + a.w * b.w;
            }
            S[i][j] = acc;
        }
        __syncthreads();

        // row softmax: 4 lanes per row
        {
            int row = tid >> 2, sub = tid & 3;
            if (row < m) {
                float mx = -3.4e38f;
                for (int j = sub; j < m; j += 4) mx = fmaxf(mx, S[row][j]);
                mx = fmaxf(mx, __shfl_xor(mx, 1));
                mx = fmaxf(mx, __shfl_xor(mx, 2));
                float sum = 0.f;
                for (int j = sub; j < m; j += 4) { float e = __expf(S[row][j] - mx); S[row][j] = e; sum += e; }
                sum += __shfl_xor(sum, 1);
                sum += __shfl_xor(sum, 2);
                if (sub == 0) rinv[row] = 1.f / sum;
            }
        }
        __syncthreads();

        // column sums of normalized weights: 4 lanes per column
        {
            int col = tid >> 2, sub = tid & 3;
            if (col < m) {
                float acc = 0.f;
                for (int i = sub; i < m; i += 4) acc += S[i][col] * rinv[i];
                acc += __shfl_xor(acc, 1);
                acc += __shfl_xor(acc, 2);
                if (sub == 0) csum[col] = acc;
            }
        }
        __syncthreads();

        // emb[d] = sum_j csum[j] * V[start+j][d], two halves then combine
        {
            int d = tid & 127, h = tid >> 7;
            float acc = 0.f;
            for (int j = h; j < m; j += 2) acc += csum[j] * Vf[(size_t)(start + j) * D_K + d];
            ((float*)S)[h * D_K + d] = acc;
            __syncthreads();
            if (tid < D_K) out[(size_t)mol * D_K + tid] = ((float*)S)[tid] + ((float*)S)[D_K + tid];
        }
        return;
    }

    // ---- slow fallback, m > MAXM (expected never on this data) ----
    {
        float* emb = &S[0][0];
        if (tid < D_K) emb[tid] = 0.f;
        float* Mv = ML;
        float* Lv = ML + n;

        for (int i = tid; i < m; i += 256) {
            const float4* q = (const float4*)(Qs + (size_t)(start + i) * D_K);
            float mx = -3.4e38f, sum = 0.f;
            for (int j = 0; j < m; ++j) {
                const float4* k = (const float4*)(Kf + (size_t)(start + j) * D_K);
                float s = 0.f;
                #pragma unroll
                for (int t = 0; t < D_K / 4; ++t) {
                    float4 a = q[t], b = k[t];
                    s += a.x * b.x + a.y * b.y + a.z * b.z + a.w * b.w;
                }
                if (s > mx) { sum = sum * __expf(mx - s) + 1.f; mx = s; }
                else        { sum += __expf(s - mx); }
            }
            Mv[start + i] = mx;
            Lv[start + i] = 1.f / sum;
        }
        __threadfence_block();
        __syncthreads();

        for (int j = tid; j < m; j += 256) {
            const float4* k = (const float4*)(Kf + (size_t)(start + j) * D_K);
            float cj = 0.f;
            for (int i = 0; i < m; ++i) {
                const float4* q = (const float4*)(Qs + (size_t)(start + i) * D_K);
                float s = 0.f;
                #pragma unroll
                for (int t = 0; t < D_K / 4; ++t) {
                    float4 a = q[t], b = k[t];
                    s += a.x * b.x + a.y * b.y + a.z * b.z + a.w * b.w;
                }
                cj += __expf(s - Mv[start + i]) * Lv[start + i];
            }
            const float* v = Vf + (size_t)(start + j) * D_K;
            for (int d = 0; d < D_K; ++d) atomicAdd(&emb[d], cj * v[d]);
        }
        __syncthreads();
        if (tid < D_K) out[(size_t)mol * D_K + tid] = emb[tid];
    }
}

extern "C" void kernel_launch(void* const* d_in, const int* in_sizes, int n_in,
                              void* d_out, int out_size, void* d_ws, size_t ws_size,
                              hipStream_t stream) {
    const float* frag = (const float*)d_in[0];
    const int*   midx = (const int*)d_in[1];
    const float* Wq = (const float*)d_in[2];
    const float* bq = (const float*)d_in[3];
    const float* Wk = (const float*)d_in[4];
    const float* bk = (const float*)d_in[5];
    const float* Wv = (const float*)d_in[6];
    const float* bv = (const float*)d_in[7];
    float* out = (float*)d_out;

    const int n = in_sizes[1];          // 8192
    const int nmol = out_size / D_K;    // 512

    float* Qs = (float*)d_ws;
    float* Ko = Qs + (size_t)n * D_K;
    float* Vo = Ko + (size_t)n * D_K;
    float* ML = Vo + (size_t)n * D_K;                  // 2*n floats (slow path)
    unsigned short* Abf = (unsigned short*)(ML + 2 * (size_t)n);
    unsigned short* Wt  = Abf + (size_t)n * D_MODEL;   // 3*128*256 bf16
    float* Bias = (float*)(Wt + 3 * (size_t)D_K * D_MODEL);

    const int nAblocks = (n * D_MODEL) / 2048;
    pack_kernel<<<nAblocks + 96 + 1, 256, 0, stream>>>(frag, Wq, bq, Wk, bk, Wv, bv, Abf, Wt, Bias, n);
    qkv_mfma<<<dim3(n / 32, 3), 256, 0, stream>>>(Abf, Wt, Bias, Qs, Ko, Vo, n);
    attn_pool<<<nmol, 256, 0, stream>>>(midx, Qs, Ko, Vo, out, ML, n);
}

// Round 4
// 31.008 us; speedup vs baseline: 2.4151x; 1.9250x over previous
//
#include <hip/hip_runtime.h>
#include <hip/hip_bf16.h>

#define D_MODEL 256
#define D_K 128
#define MAXM 40     // fast-path molecule size cap (3 row-tiles of 16)
#define CH 48       // row capacity per tile pass

typedef short bf16x8 __attribute__((ext_vector_type(8)));
typedef float f32x4 __attribute__((ext_vector_type(4)));

__device__ inline unsigned short f2bf(float x) {
    union { float f; unsigned u; } v; v.f = x;
    unsigned r = v.u + 0x7FFFu + ((v.u >> 16) & 1u);  // RNE (finite inputs)
    return (unsigned short)(r >> 16);
}
__device__ inline float bf2f(unsigned short h) {
    union { unsigned u; float f; } v; v.u = ((unsigned)h) << 16; return v.f;
}

__device__ inline int lbound(const int* __restrict__ p, int stride, int n, int val) {
    int lo = 0, hi = n;
    while (lo < hi) {
        int mid = (lo + hi) >> 1;
        if (p[(size_t)mid * stride] < val) lo = mid + 1; else hi = mid;
    }
    return lo;
}

// ---- LDS layout (bytes). Total 57,344 -> 2 blocks/CU ----
// At  [CH][256] bf16, XOR-swizzled rows (bits 4-6)     : [0, 24576)
// Vb  [CH][136] bf16 (aliases At after QKV barrier)    : [0, 13056)
// Qb  [CH][136] bf16                                   : [24576, 37632)
// Kb  [CH][136] bf16                                   : [37632, 50688)
// S   [CH][52]  bf16                                   : [50688, 55680)
// rinv f32[CH]                                         : [55680, 55872)
// csum f32[CH]                                         : [55872, 56064)
// emb  f32[2][128]                                     : [56064, 57088)
#define AT_BYTE(r, c2) (((r) << 9) + ((((c2) << 1)) ^ (((r) & 7) << 4)))

// Shared QKV tile pass: At(LDS) x Wt(global) -> acc[6][3]
// ct = wave + cl*4 covers 24 col-tiles (Q 0-7, K 8-15, V 16-23), rt covers 3 row-tiles.
__device__ __forceinline__ void qkv_tiles(
    const unsigned char* lds, const unsigned short* __restrict__ Wt,
    int wave, int lr, int lk8, f32x4 (&acc)[6][3])
{
    #pragma unroll
    for (int cl = 0; cl < 6; ++cl) {
        const int ct = wave + cl * 4;
        const unsigned short* wrow = Wt + (size_t)(ct * 16 + lr) * D_MODEL + lk8;
        #pragma unroll
        for (int k0 = 0; k0 < 8; ++k0) {
            bf16x8 bf = *(const bf16x8*)(wrow + k0 * 32);
            #pragma unroll
            for (int rt = 0; rt < 3; ++rt) {
                bf16x8 af = *(const bf16x8*)(lds + AT_BYTE(rt * 16 + lr, k0 * 32 + lk8));
                acc[cl][rt] = __builtin_amdgcn_mfma_f32_16x16x32_bf16(af, bf, acc[cl][rt], 0, 0, 0);
            }
        }
    }
}

// ---------------- prep: W pack/transpose + bias + segment boundaries ----------------
__global__ __launch_bounds__(256) void prep(
    const float* __restrict__ Wq, const float* __restrict__ bq,
    const float* __restrict__ Wk, const float* __restrict__ bk,
    const float* __restrict__ Wv, const float* __restrict__ bv,
    const int* __restrict__ midx,
    unsigned short* __restrict__ Wt, float* __restrict__ Bias, int* __restrict__ Seg,
    int n, int nmol)
{
    const int tid = threadIdx.x, blk = blockIdx.x;
    const float qs = 0.08838834764831845f; // 1/sqrt(128)
    if (blk < 96) {
        // 3*256*128 elems; Wt layout: [which*128 + col][k]
        int e = blk * 1024 + tid * 4;
        int which = e >> 15, rem = e & 32767;
        int r = rem >> 7, c = rem & 127;
        const float* W = which == 0 ? Wq : (which == 1 ? Wk : Wv);
        float sc = which == 0 ? qs : 1.f;
        float4 w = *(const float4*)&W[(size_t)r * D_K + c];
        unsigned short* dst = Wt + (size_t)which * D_K * D_MODEL;
        dst[(size_t)(c + 0) * D_MODEL + r] = f2bf(w.x * sc);
        dst[(size_t)(c + 1) * D_MODEL + r] = f2bf(w.y * sc);
        dst[(size_t)(c + 2) * D_MODEL + r] = f2bf(w.z * sc);
        dst[(size_t)(c + 3) * D_MODEL + r] = f2bf(w.w * sc);
    } else if (blk == 96) {
        for (int t = tid; t < 3 * D_K; t += 256) {
            int which = t >> 7, c = t & 127;
            const float* b = which == 0 ? bq : (which == 1 ? bk : bv);
            Bias[t] = b[c] * (which == 0 ? qs : 1.f);
        }
    } else {
        // int64 detection: sorted int64 high words are 0 -> last int32 slot == 0
        int stride = (midx[n - 1] == 0) ? 2 : 1;
        for (int v = tid; v <= nmol; v += 256) Seg[v] = lbound(midx, stride, n, v);
    }
}

// ---------------- fused: per-molecule QKV (MFMA) + attention + pooling ----------------
__global__ __launch_bounds__(256, 2) void fused(
    const float* __restrict__ A, const unsigned short* __restrict__ Wt,
    const float* __restrict__ Bias, const int* __restrict__ Seg,
    float* __restrict__ out,
    float* __restrict__ Qw, float* __restrict__ Kw, float* __restrict__ Vw,
    float* __restrict__ ML, int n)
{
    __shared__ __align__(16) unsigned char lds[57088];
    unsigned short* Qb = (unsigned short*)(lds + 24576);
    unsigned short* Kb = (unsigned short*)(lds + 37632);
    unsigned short* Vb = (unsigned short*)(lds);        // aliases At (after barrier)
    unsigned short* S  = (unsigned short*)(lds + 50688);
    float* rinv = (float*)(lds + 55680);
    float* csum = (float*)(lds + 55872);
    float* emb  = (float*)(lds + 56064);

    const int tid = threadIdx.x, mol = blockIdx.x;
    const int wave = tid >> 6, lane = tid & 63;
    const int lr = lane & 15, lk8 = (lane >> 4) * 8;
    const int s = Seg[mol], e = Seg[mol + 1];
    const int m = e - s;

    if (m == 0) {
        if (tid < D_K) out[(size_t)mol * D_K + tid] = 0.f;
        return;
    }

    if (m <= MAXM) {
        // ---- stage A rows -> At bf16 (zero-pad to CH rows) ----
        #pragma unroll
        for (int it = 0; it < (CH * 256) / 1024; ++it) {   // 12
            int eidx = tid * 4 + it * 1024;
            int r = eidx >> 8, c = eidx & 255;
            float4 a;
            if (r < m) a = *(const float4*)&A[(size_t)(s + r) * D_MODEL + c];
            else       a = make_float4(0.f, 0.f, 0.f, 0.f);
            unsigned short o[4] = {f2bf(a.x), f2bf(a.y), f2bf(a.z), f2bf(a.w)};
            *(unsigned long long*)(lds + AT_BYTE(r, c)) = *(const unsigned long long*)o;
        }
        __syncthreads();

        // ---- QKV MFMA ----
        f32x4 acc[6][3];
        #pragma unroll
        for (int i = 0; i < 6; ++i)
            #pragma unroll
            for (int j = 0; j < 3; ++j) acc[i][j] = {0.f, 0.f, 0.f, 0.f};
        qkv_tiles(lds, Wt, wave, lr, lk8, acc);
        __syncthreads();   // all At reads done; Vb may overwrite

        // ---- write Q,K,V (+bias) to LDS bf16 ----
        #pragma unroll
        for (int cl = 0; cl < 6; ++cl) {
            int ct = wave + cl * 4;
            int which = ct >> 3;
            int col = (ct & 7) * 16 + lr;
            float bb = Bias[which * D_K + col];
            unsigned short* dst = which == 0 ? Qb : (which == 1 ? Kb : Vb);
            #pragma unroll
            for (int rt = 0; rt < 3; ++rt) {
                int rbase = rt * 16 + (lane >> 4) * 4;
                #pragma unroll
                for (int r = 0; r < 4; ++r)
                    dst[(rbase + r) * 136 + col] = f2bf(acc[cl][rt][r] + bb);
            }
        }
        __syncthreads();

        // ---- scores via MFMA: S[i][j] = Q_i . K_j (scale folded into Wq) ----
        for (int job = wave; job < 9; job += 4) {
            int ti = job / 3, tj = job % 3;
            f32x4 sa = {0.f, 0.f, 0.f, 0.f};
            #pragma unroll
            for (int kk = 0; kk < 4; ++kk) {
                bf16x8 qf = *(const bf16x8*)&Qb[(ti * 16 + lr) * 136 + kk * 32 + lk8];
                bf16x8 kf = *(const bf16x8*)&Kb[(tj * 16 + lr) * 136 + kk * 32 + lk8];
                sa = __builtin_amdgcn_mfma_f32_16x16x32_bf16(qf, kf, sa, 0, 0, 0);
            }
            int jcol = tj * 16 + lr, ibase = ti * 16 + (lane >> 4) * 4;
            #pragma unroll
            for (int r = 0; r < 4; ++r)
                S[(ibase + r) * 52 + jcol] = f2bf(sa[r]);
        }
        __syncthreads();

        // ---- row softmax: 4 lanes per row ----
        {
            int row = tid >> 2, sub = tid & 3;
            if (row < m) {
                float mx = -3.4e38f;
                for (int j = sub; j < m; j += 4) mx = fmaxf(mx, bf2f(S[row * 52 + j]));
                mx = fmaxf(mx, __shfl_xor(mx, 1));
                mx = fmaxf(mx, __shfl_xor(mx, 2));
                float sum = 0.f;
                for (int j = sub; j < m; j += 4) {
                    float ev = __expf(bf2f(S[row * 52 + j]) - mx);
                    S[row * 52 + j] = f2bf(ev);
                    sum += ev;
                }
                sum += __shfl_xor(sum, 1);
                sum += __shfl_xor(sum, 2);
                if (sub == 0) rinv[row] = 1.f / sum;
            }
        }
        __syncthreads();

        // ---- column sums of normalized weights ----
        {
            int col = tid >> 2, sub = tid & 3;
            if (col < m) {
                float a = 0.f;
                for (int i = sub; i < m; i += 4) a += bf2f(S[i * 52 + col]) * rinv[i];
                a += __shfl_xor(a, 1);
                a += __shfl_xor(a, 2);
                if (sub == 0) csum[col] = a;
            }
        }
        __syncthreads();

        // ---- emb[d] = sum_j csum[j] * V[j][d] ----
        {
            int d = tid & 127, h = tid >> 7;
            float a = 0.f;
            for (int j = h; j < m; j += 2) a += csum[j] * bf2f(Vb[j * 136 + d]);
            emb[h * D_K + d] = a;
            __syncthreads();
            if (tid < D_K) out[(size_t)mol * D_K + tid] = emb[tid] + emb[D_K + tid];
        }
        return;
    }

    // ================= slow fallback (m > MAXM): chunked QKV to global, then streaming =================
    for (int r0 = 0; r0 < m; r0 += CH) {
        #pragma unroll
        for (int it = 0; it < (CH * 256) / 1024; ++it) {
            int eidx = tid * 4 + it * 1024;
            int r = eidx >> 8, c = eidx & 255;
            float4 a;
            if (r0 + r < m) a = *(const float4*)&A[(size_t)(s + r0 + r) * D_MODEL + c];
            else            a = make_float4(0.f, 0.f, 0.f, 0.f);
            unsigned short o[4] = {f2bf(a.x), f2bf(a.y), f2bf(a.z), f2bf(a.w)};
            *(unsigned long long*)(lds + AT_BYTE(r, c)) = *(const unsigned long long*)o;
        }
        __syncthreads();

        f32x4 acc[6][3];
        #pragma unroll
        for (int i = 0; i < 6; ++i)
            #pragma unroll
            for (int j = 0; j < 3; ++j) acc[i][j] = {0.f, 0.f, 0.f, 0.f};
        qkv_tiles(lds, Wt, wave, lr, lk8, acc);

        #pragma unroll
        for (int cl = 0; cl < 6; ++cl) {
            int ct = wave + cl * 4;
            int which = ct >> 3;
            int col = (ct & 7) * 16 + lr;
            float bb = Bias[which * D_K + col];
            float* dst = which == 0 ? Qw : (which == 1 ? Kw : Vw);
            #pragma unroll
            for (int rt = 0; rt < 3; ++rt) {
                int rbase = rt * 16 + (lane >> 4) * 4;
                #pragma unroll
                for (int r = 0; r < 4; ++r) {
                    int lrow = rbase + r;
                    if (r0 + lrow < m)
                        dst[(size_t)(s + r0 + lrow) * D_K + col] = acc[cl][rt][r] + bb;
                }
            }
        }
        __syncthreads();   // At free for next chunk
    }

    // streaming two-phase attention from global Q/K/V
    if (tid < D_K) emb[tid] = 0.f;
    float* Mv = ML;
    float* Lv = ML + n;
    __syncthreads();

    for (int i = tid; i < m; i += 256) {
        const float4* q = (const float4*)(Qw + (size_t)(s + i) * D_K);
        float mx = -3.4e38f, sum = 0.f;
        for (int j = 0; j < m; ++j) {
            const float4* k = (const float4*)(Kw + (size_t)(s + j) * D_K);
            float sc = 0.f;
            #pragma unroll
            for (int t = 0; t < D_K / 4; ++t) {
                float4 a = q[t], b = k[t];
                sc += a.x * b.x + a.y * b.y + a.z * b.z + a.w * b.w;
            }
            if (sc > mx) { sum = sum * __expf(mx - sc) + 1.f; mx = sc; }
            else         { sum += __expf(sc - mx); }
        }
        Mv[s + i] = mx;
        Lv[s + i] = 1.f / sum;
    }
    __threadfence_block();
    __syncthreads();

    for (int j = tid; j < m; j += 256) {
        const float4* k = (const float4*)(Kw + (size_t)(s + j) * D_K);
        float cj = 0.f;
        for (int i = 0; i < m; ++i) {
            const float4* q = (const float4*)(Qw + (size_t)(s + i) * D_K);
            float sc = 0.f;
            #pragma unroll
            for (int t = 0; t < D_K / 4; ++t) {
                float4 a = q[t], b = k[t];
                sc += a.x * b.x + a.y * b.y + a.z * b.z + a.w * b.w;
            }
            cj += __expf(sc - Mv[s + i]) * Lv[s + i];
        }
        const float* v = Vw + (size_t)(s + j) * D_K;
        for (int d = 0; d < D_K; ++d) atomicAdd(&emb[d], cj * v[d]);
    }
    __syncthreads();
    if (tid < D_K) out[(size_t)mol * D_K + tid] = emb[tid];
}

extern "C" void kernel_launch(void* const* d_in, const int* in_sizes, int n_in,
                              void* d_out, int out_size, void* d_ws, size_t ws_size,
                              hipStream_t stream) {
    const float* frag = (const float*)d_in[0];
    const int*   midx = (const int*)d_in[1];
    const float* Wq = (const float*)d_in[2];
    const float* bq = (const float*)d_in[3];
    const float* Wk = (const float*)d_in[4];
    const float* bk = (const float*)d_in[5];
    const float* Wv = (const float*)d_in[6];
    const float* bv = (const float*)d_in[7];
    float* out = (float*)d_out;

    const int n = in_sizes[1];          // 8192
    const int nmol = out_size / D_K;    // 512

    float* Qw = (float*)d_ws;
    float* Kw = Qw + (size_t)n * D_K;
    float* Vw = Kw + (size_t)n * D_K;
    float* ML = Vw + (size_t)n * D_K;                    // 2*n floats
    unsigned short* Wt = (unsigned short*)(ML + 2 * (size_t)n);
    float* Bias = (float*)(Wt + 3 * (size_t)D_K * D_MODEL);
    int* Seg = (int*)(Bias + 3 * D_K);

    prep<<<98, 256, 0, stream>>>(Wq, bq, Wk, bk, Wv, bv, midx, Wt, Bias, Seg, n, nmol);
    fused<<<nmol, 256, 0, stream>>>(frag, Wt, Bias, Seg, out, Qw, Kw, Vw, ML, n);
}